// Round 2
// baseline (3012.100 us; speedup 1.0000x reference)
//
#include <hip/hip_runtime.h>
#include <stdint.h>

#define BATCH 64
#define TT    150
#define INSZ  120
#define HID   1024
#define OUTN  35
#define NBR   8

// ---------------- workspace layout (bytes) ----------------
#define XT_OFF  0
#define S1_OFF  4608000
#define S2_OFF  5836800
#define S3_OFF  7065600
#define Y_OFF   8294400
#define ACC_OFF 9638400

// transpose x[b][0][t][i] -> xT[t][i][b]
__global__ void k_tx(const float* __restrict__ x, float* __restrict__ xT) {
    const int total = BATCH * TT * INSZ;
    for (int e = blockIdx.x * blockDim.x + threadIdx.x; e < total;
         e += gridDim.x * blockDim.x) {
        const int b = e / (TT * INSZ);
        const int r = e - b * (TT * INSZ);   // t*INSZ + i
        xT[(size_t)r * 64 + b] = x[e];
    }
}

// One recurrent layer, scans all T steps. 256 blocks x 1024 threads.
// block owns 4 neurons; wave (64 lanes = 64 batches) owns 2 branch-rows.
// MODE 0: dense float input from xT. MODE 1: spike-mask input.
template <int DIN, int NNZ, int MODE>
__global__ __launch_bounds__(1024, 4) void k_layer(
    const float* __restrict__ w,            // [HID*NBR, DIN]
    const void* __restrict__ maskp,         // [HID*NBR, DIN] bool (u8 or i32)
    const float* __restrict__ bias,         // [HID*NBR]
    const float* __restrict__ tau_m,        // [HID]
    const float* __restrict__ tau_n,        // [HID*NBR]
    const float* __restrict__ xin,          // MODE0: [T][DIN][64]
    const uint64_t* __restrict__ inm,       // MODE1: [T][DIN]
    uint64_t* __restrict__ outm)            // [T][HID]
{
    constexpr int CH = 6;                   // 150 = 25 * 6
    const int tid  = threadIdx.x;
    const int lane = tid & 63;
    const int wid  = tid >> 6;              // 0..15
    const int nl   = wid >> 2;              // local neuron 0..3
    const int pb   = wid & 3;               // branch pair 0..3
    const int h    = blockIdx.x * 4 + nl;
    const int r0   = h * NBR + pb * 2;      // this wave's 2 rows

    __shared__ uint2 ent[16 * 2 * NNZ];                 // (w bits, idx)
    __shared__ float red[4 * 4 * CH * 64];

    // ---- gather masked weights into LDS (ballot compaction) ----
    // mask dtype unknown (u8 bool or promoted i32): try u8; if the row's
    // nnz != NNZ (known exactly from construction), redo as i32.
    const unsigned char* m8  = (const unsigned char*)maskp;
    const int*           m32 = (const int*)maskp;
    for (int rl = 0; rl < 2; ++rl) {
        const int r    = r0 + rl;
        const int base = (wid * 2 + rl) * NNZ;
        int cnt = 0;
        for (int c = 0; c * 64 < DIN; ++c) {
            const int i = c * 64 + lane;
            int   mv = 0;
            float wv = 0.f;
            if (i < DIN) {
                mv = m8[(size_t)r * DIN + i];
                wv = w[(size_t)r * DIN + i];
            }
            const unsigned long long bal = __ballot(mv != 0);
            const int pos = __popcll(bal & ((1ull << lane) - 1ull));
            if (mv && cnt + pos < NNZ)
                ent[base + cnt + pos] = make_uint2(__float_as_uint(wv), (unsigned)i);
            cnt += __popcll(bal);
        }
        if (cnt != NNZ) {   // masks are int32 after all
            cnt = 0;
            for (int c = 0; c * 64 < DIN; ++c) {
                const int i = c * 64 + lane;
                int   mv = 0;
                float wv = 0.f;
                if (i < DIN) {
                    mv = m32[(size_t)r * DIN + i];
                    wv = w[(size_t)r * DIN + i];
                }
                const unsigned long long bal = __ballot(mv != 0);
                const int pos = __popcll(bal & ((1ull << lane) - 1ull));
                if (mv) ent[base + cnt + pos] =
                            make_uint2(__float_as_uint(wv), (unsigned)i);
                cnt += __popcll(bal);
            }
        }
    }
    __syncthreads();

    const float be0 = 1.f / (1.f + expf(-tau_n[r0]));
    const float be1 = 1.f / (1.f + expf(-tau_n[r0 + 1]));
    const float om0 = 1.f - be0, om1 = 1.f - be1;
    const float bb0 = bias[r0], bb1 = bias[r0 + 1];
    const float al  = 1.f / (1.f + expf(-tau_m[h]));
    const float oma = 1.f - al;

    float d0 = 0.f, d1 = 0.f, mem = 0.f, spkprev = 0.f;
    const int base0 = (wid * 2 + 0) * NNZ;
    const int base1 = (wid * 2 + 1) * NNZ;

    for (int t0 = 0; t0 < TT; t0 += CH) {
        float a0[CH], a1[CH];
#pragma unroll
        for (int k = 0; k < CH; ++k) { a0[k] = 0.f; a1[k] = 0.f; }

        if constexpr (MODE == 1) {
            const uint64_t* mbase = inm + (size_t)t0 * DIN;
#pragma unroll 2
            for (int j = 0; j < NNZ; ++j) {
                {
                    const uint2 e  = ent[base0 + j];
                    const int   ix = __builtin_amdgcn_readfirstlane((int)e.y);
                    const float wv = __uint_as_float(e.x);
                    const uint64_t* mp = mbase + ix;
#pragma unroll
                    for (int k = 0; k < CH; ++k) {
                        const uint64_t m = mp[(size_t)k * DIN];
                        float s;
                        asm("v_cndmask_b32 %0, 0, %1, %2"
                            : "=v"(s) : "v"(wv), "s"(m));
                        a0[k] += s;
                    }
                }
                {
                    const uint2 e  = ent[base1 + j];
                    const int   ix = __builtin_amdgcn_readfirstlane((int)e.y);
                    const float wv = __uint_as_float(e.x);
                    const uint64_t* mp = mbase + ix;
#pragma unroll
                    for (int k = 0; k < CH; ++k) {
                        const uint64_t m = mp[(size_t)k * DIN];
                        float s;
                        asm("v_cndmask_b32 %0, 0, %1, %2"
                            : "=v"(s) : "v"(wv), "s"(m));
                        a1[k] += s;
                    }
                }
            }
        } else {
            const float* xb = xin + (size_t)t0 * DIN * 64;
            for (int j = 0; j < NNZ; ++j) {
                {
                    const uint2 e  = ent[base0 + j];
                    const int   ix = __builtin_amdgcn_readfirstlane((int)e.y);
                    const float wv = __uint_as_float(e.x);
#pragma unroll
                    for (int k = 0; k < CH; ++k)
                        a0[k] += wv * xb[((size_t)k * DIN + ix) * 64 + lane];
                }
                {
                    const uint2 e  = ent[base1 + j];
                    const int   ix = __builtin_amdgcn_readfirstlane((int)e.y);
                    const float wv = __uint_as_float(e.x);
#pragma unroll
                    for (int k = 0; k < CH; ++k)
                        a1[k] += wv * xb[((size_t)k * DIN + ix) * 64 + lane];
                }
            }
        }

        // branch decay (sequential within chunk), stash pair partial sums
        float pr[CH];
#pragma unroll
        for (int k = 0; k < CH; ++k) {
            d0 = be0 * d0 + om0 * (a0[k] + bb0);
            d1 = be1 * d1 + om1 * (a1[k] + bb1);
            pr[k] = d0 + d1;
        }
#pragma unroll
        for (int k = 0; k < CH; ++k)
            red[((nl * 4 + pb) * CH + k) * 64 + lane] = pr[k];
        __syncthreads();

        if (pb == 0) {
#pragma unroll
            for (int k = 0; k < CH; ++k) {
                const int rb = nl * 4 * CH;
                float l = red[(rb + 0 * CH + k) * 64 + lane]
                        + red[(rb + 1 * CH + k) * 64 + lane]
                        + red[(rb + 2 * CH + k) * 64 + lane]
                        + red[(rb + 3 * CH + k) * 64 + lane];
                mem = al * mem + oma * l - spkprev;     // VTH = 1.0
                spkprev = (mem > 1.0f) ? 1.f : 0.f;
                const unsigned long long bal = __ballot(mem > 1.0f);
                if (lane == 0) outm[(size_t)(t0 + k) * HID + h] = bal;
            }
        }
        __syncthreads();
    }
}

// Y[t][o][b] = wr[o] . s3(t, :, b)   — ONE WAVE PER BLOCK so that the
// mask address is provably uniform (scalar loads -> "s" asm constraint ok).
__global__ __launch_bounds__(64) void k_ry(const float* __restrict__ wr,
                                           const uint64_t* __restrict__ s3m,
                                           float* __restrict__ Y) {
    const int lane = threadIdx.x;
    const int wg   = blockIdx.x;            // t * OUTN + o
    const int t = wg / OUTN, o = wg - t * OUTN;
    const uint64_t* mrow = s3m + (size_t)t * HID;
    const float*    wrow = wr + (size_t)o * HID;
    float acc = 0.f;
#pragma unroll 8
    for (int i = 0; i < HID; ++i) {
        const uint64_t m  = mrow[i];
        const float    wv = wrow[i];
        float s;
        asm("v_cndmask_b32 %0, 0, %1, %2" : "=v"(s) : "v"(wv), "s"(m));
        acc += s;
    }
    Y[((size_t)t * OUTN + o) * 64 + lane] = acc;
}

// acc[o][b] = sum_t (Y + br[o]) * (1 - ar^(150-t))   (closed-form mr scan)
__global__ void k_racc(const float* __restrict__ Y,
                       const float* __restrict__ br,
                       const float* __restrict__ tau_mr,
                       float* __restrict__ ACC) {
    const int o = blockIdx.x, lane = threadIdx.x;
    const float ar  = 1.f / (1.f + expf(-tau_mr[o]));
    const float bro = br[o];
    float acc = 0.f, q = ar;
    for (int t = TT - 1; t >= 0; --t) {
        const float y = Y[((size_t)t * OUTN + o) * 64 + lane] + bro;
        acc += y * (1.f - q);
        q *= ar;
    }
    ACC[o * 64 + lane] = acc;
}

__global__ void k_smax(const float* __restrict__ ACC, float* __restrict__ out) {
    const int b = threadIdx.x;   // 64 threads
    float v[OUTN];
    float mx = -3.4e38f;
    for (int o = 0; o < OUTN; ++o) {
        v[o] = ACC[o * 64 + b] / (float)TT;
        mx = fmaxf(mx, v[o]);
    }
    float sum = 0.f;
    for (int o = 0; o < OUTN; ++o) sum += expf(v[o] - mx);
    const float lse = mx + logf(sum);
    for (int o = 0; o < OUTN; ++o) out[b * OUTN + o] = v[o] - lse;
}

extern "C" void kernel_launch(void* const* d_in, const int* in_sizes, int n_in,
                              void* d_out, int out_size, void* d_ws,
                              size_t ws_size, hipStream_t stream) {
    (void)in_sizes; (void)n_in; (void)out_size; (void)ws_size;
    const float* x   = (const float*)d_in[0];
    const float* w1  = (const float*)d_in[1];
    const float* b1  = (const float*)d_in[2];
    const float* tm1 = (const float*)d_in[3];
    const float* tn1 = (const float*)d_in[4];
    const float* w2  = (const float*)d_in[5];
    const float* b2  = (const float*)d_in[6];
    const float* tm2 = (const float*)d_in[7];
    const float* tn2 = (const float*)d_in[8];
    const float* w3  = (const float*)d_in[9];
    const float* b3  = (const float*)d_in[10];
    const float* tm3 = (const float*)d_in[11];
    const float* tn3 = (const float*)d_in[12];
    const float* wr  = (const float*)d_in[13];
    const float* br  = (const float*)d_in[14];
    const float* tmr = (const float*)d_in[15];
    const void*  m1  = d_in[16];
    const void*  m2  = d_in[17];
    const void*  m3  = d_in[18];
    float* out = (float*)d_out;

    char* ws = (char*)d_ws;
    float*    xT  = (float*)(ws + XT_OFF);
    uint64_t* s1m = (uint64_t*)(ws + S1_OFF);
    uint64_t* s2m = (uint64_t*)(ws + S2_OFF);
    uint64_t* s3m = (uint64_t*)(ws + S3_OFF);
    float*    Y   = (float*)(ws + Y_OFF);
    float*    ACC = (float*)(ws + ACC_OFF);

    k_tx<<<1024, 256, 0, stream>>>(x, xT);
    k_layer<INSZ, 15, 0><<<256, 1024, 0, stream>>>(
        w1, m1, b1, tm1, tn1, xT, nullptr, s1m);
    k_layer<HID, 128, 1><<<256, 1024, 0, stream>>>(
        w2, m2, b2, tm2, tn2, nullptr, s1m, s2m);
    k_layer<HID, 128, 1><<<256, 1024, 0, stream>>>(
        w3, m3, b3, tm3, tn3, nullptr, s2m, s3m);
    k_ry<<<TT * OUTN, 64, 0, stream>>>(wr, s3m, Y);
    k_racc<<<OUTN, 64, 0, stream>>>(Y, br, tmr, ACC);
    k_smax<<<1, 64, 0, stream>>>(ACC, out);
}

// Round 3
// 2454.330 us; speedup vs baseline: 1.2273x; 1.2273x over previous
//
#include <hip/hip_runtime.h>
#include <stdint.h>

#define BATCH 64
#define TT    150
#define INSZ  120
#define HID   1024
#define OUTN  35
#define NBR   8
#define TPAD  160      // padded T (u64 masks), keeps chunk starts 64B-aligned
#define CH    8        // timesteps per chunk (19 chunks, last has 6 valid)

// ---------------- workspace layout (bytes, all 64-aligned) ----------------
#define XT_OFF  0                  // xT  [150][120][64] f32 = 4,608,000
#define S1_OFF  4608000            // s1m [1024][160] u64    = 1,310,720
#define S2_OFF  5918720            // s2m
#define S3_OFF  7229440            // s3m
#define Y_OFF   8540160            // Y   [150][35][64] f32  = 1,344,000
#define ACC_OFF 9884160            // ACC [35][64] f32       = 8,960

// transpose x[b][0][t][i] -> xT[t][i][b], LDS-tiled (both sides coalesced)
__global__ __launch_bounds__(256) void k_tx(const float* __restrict__ x,
                                            float* __restrict__ xT) {
    const int t = blockIdx.x;
    __shared__ float tile[INSZ * 65];
    for (int e = threadIdx.x; e < INSZ * 64; e += 256) {
        const int b = e / INSZ, i = e - b * INSZ;
        tile[i * 65 + b] = x[((size_t)b * TT + t) * INSZ + i];
    }
    __syncthreads();
    for (int e = threadIdx.x; e < INSZ * 64; e += 256) {
        const int i = e >> 6, b = e & 63;
        xT[((size_t)t * INSZ + i) * 64 + b] = tile[i * 65 + b];
    }
}

// One recurrent layer, scans all T steps. grid = HID blocks x 256 threads.
// Block owns 1 neuron (8 branch rows); each wave (64 lanes = 64 batches)
// owns 2 rows. MODE 0: dense float input from xT. MODE 1: spike masks
// in transposed layout inm[i*TPAD + t].
template <int DIN, int NNZ, int MODE>
__global__ __launch_bounds__(256, 4) void k_layer(
    const float* __restrict__ w,            // [HID*NBR, DIN]
    const void* __restrict__ maskp,         // [HID*NBR, DIN] bool (u8 or i32)
    const float* __restrict__ bias,         // [HID*NBR]
    const float* __restrict__ tau_m,        // [HID]
    const float* __restrict__ tau_n,        // [HID*NBR]
    const float* __restrict__ xin,          // MODE0: [T][DIN][64]
    const uint64_t* __restrict__ inm,       // MODE1: [DIN][TPAD]
    uint64_t* __restrict__ outm)            // [HID][TPAD]
{
    const int tid  = threadIdx.x;
    const int lane = tid & 63;
    const int wid  = tid >> 6;              // 0..3 (branch pair)
    const int h    = blockIdx.x;
    const int r0   = h * NBR + wid * 2;     // this wave's 2 rows

    __shared__ uint2 ent[NBR * NNZ];        // (w bits, idx) per row
    __shared__ float red[4 * CH * 64];

    inm = (const uint64_t*)__builtin_assume_aligned(inm, 64);

    // ---- gather masked weights into LDS (ballot compaction) ----
    const unsigned char* m8  = (const unsigned char*)maskp;
    const int*           m32 = (const int*)maskp;
    for (int rl = 0; rl < 2; ++rl) {
        const int r    = r0 + rl;
        const int base = (wid * 2 + rl) * NNZ;
        int cnt = 0;
        for (int c = 0; c * 64 < DIN; ++c) {
            const int i = c * 64 + lane;
            int   mv = 0;
            float wv = 0.f;
            if (i < DIN) {
                mv = m8[(size_t)r * DIN + i];
                wv = w[(size_t)r * DIN + i];
            }
            const unsigned long long bal = __ballot(mv != 0);
            const int pos = __popcll(bal & ((1ull << lane) - 1ull));
            if (mv && cnt + pos < NNZ)
                ent[base + cnt + pos] = make_uint2(__float_as_uint(wv), (unsigned)i);
            cnt += __popcll(bal);
        }
        if (cnt != NNZ) {   // masks are int32 after all
            cnt = 0;
            for (int c = 0; c * 64 < DIN; ++c) {
                const int i = c * 64 + lane;
                int   mv = 0;
                float wv = 0.f;
                if (i < DIN) {
                    mv = m32[(size_t)r * DIN + i];
                    wv = w[(size_t)r * DIN + i];
                }
                const unsigned long long bal = __ballot(mv != 0);
                const int pos = __popcll(bal & ((1ull << lane) - 1ull));
                if (mv) ent[base + cnt + pos] =
                            make_uint2(__float_as_uint(wv), (unsigned)i);
                cnt += __popcll(bal);
            }
        }
    }
    __syncthreads();

    const float be0 = 1.f / (1.f + expf(-tau_n[r0]));
    const float be1 = 1.f / (1.f + expf(-tau_n[r0 + 1]));
    const float om0 = 1.f - be0, om1 = 1.f - be1;
    const float bb0 = bias[r0], bb1 = bias[r0 + 1];
    const float al  = 1.f / (1.f + expf(-tau_m[h]));
    const float oma = 1.f - al;

    float d0 = 0.f, d1 = 0.f, mem = 0.f, spkprev = 0.f;
    const int base0 = (wid * 2 + 0) * NNZ;
    const int base1 = (wid * 2 + 1) * NNZ;

    for (int tc = 0; tc < (TT + CH - 1) / CH; ++tc) {
        const int t0 = tc * CH;
        float a0[CH], a1[CH];
#pragma unroll
        for (int k = 0; k < CH; ++k) { a0[k] = 0.f; a1[k] = 0.f; }

        if constexpr (MODE == 1) {
#pragma unroll 2
            for (int j = 0; j < NNZ; ++j) {
                const uint2 e0 = ent[base0 + j];
                const uint2 e1 = ent[base1 + j];
                const int ix0 = __builtin_amdgcn_readfirstlane((int)e0.y);
                const int ix1 = __builtin_amdgcn_readfirstlane((int)e1.y);
                const float w0 = __uint_as_float(e0.x);
                const float w1 = __uint_as_float(e1.x);
                const ulonglong4* p0 =
                    (const ulonglong4*)(inm + (size_t)ix0 * TPAD + t0);
                const ulonglong4* p1 =
                    (const ulonglong4*)(inm + (size_t)ix1 * TPAD + t0);
                const ulonglong4 ma0 = p0[0], mb0 = p0[1];
                const ulonglong4 ma1 = p1[0], mb1 = p1[1];
                uint64_t m0[CH] = {ma0.x, ma0.y, ma0.z, ma0.w,
                                   mb0.x, mb0.y, mb0.z, mb0.w};
                uint64_t m1[CH] = {ma1.x, ma1.y, ma1.z, ma1.w,
                                   mb1.x, mb1.y, mb1.z, mb1.w};
#pragma unroll
                for (int k = 0; k < CH; ++k) {
                    float s0, s1;
                    asm("v_cndmask_b32 %0, 0, %1, %2"
                        : "=v"(s0) : "v"(w0), "s"(m0[k]));
                    a0[k] += s0;
                    asm("v_cndmask_b32 %0, 0, %1, %2"
                        : "=v"(s1) : "v"(w1), "s"(m1[k]));
                    a1[k] += s1;
                }
            }
        } else {
            const float* xb = xin + (size_t)t0 * DIN * 64;
            for (int j = 0; j < NNZ; ++j) {
                const uint2 e0 = ent[base0 + j];
                const uint2 e1 = ent[base1 + j];
                const int ix0 = __builtin_amdgcn_readfirstlane((int)e0.y);
                const int ix1 = __builtin_amdgcn_readfirstlane((int)e1.y);
                const float w0 = __uint_as_float(e0.x);
                const float w1 = __uint_as_float(e1.x);
#pragma unroll
                for (int k = 0; k < CH; ++k) {
                    a0[k] += w0 * xb[((size_t)k * DIN + ix0) * 64 + lane];
                    a1[k] += w1 * xb[((size_t)k * DIN + ix1) * 64 + lane];
                }
            }
        }

        // branch decay (sequential within chunk), stash pair partial sums
#pragma unroll
        for (int k = 0; k < CH; ++k) {
            d0 = be0 * d0 + om0 * (a0[k] + bb0);
            d1 = be1 * d1 + om1 * (a1[k] + bb1);
            red[(wid * CH + k) * 64 + lane] = d0 + d1;
        }
        __syncthreads();

        if (wid == 0) {
#pragma unroll
            for (int k = 0; k < CH; ++k) {
                float l = red[(0 * CH + k) * 64 + lane]
                        + red[(1 * CH + k) * 64 + lane]
                        + red[(2 * CH + k) * 64 + lane]
                        + red[(3 * CH + k) * 64 + lane];
                if (t0 + k < TT) {
                    mem = al * mem + oma * l - spkprev;   // VTH = 1.0
                    spkprev = (mem > 1.0f) ? 1.f : 0.f;
                    const unsigned long long bal = __ballot(mem > 1.0f);
                    if (lane == 0) outm[(size_t)h * TPAD + (t0 + k)] = bal;
                }
            }
        }
        __syncthreads();
    }
}

// Y[t][o][b] = wr[o] . s3(t,:,b); t-tiled to use contiguous transposed masks
__global__ __launch_bounds__(64) void k_ry(const float* __restrict__ wr,
                                           const uint64_t* __restrict__ s3m,
                                           float* __restrict__ Y) {
    const int lane = threadIdx.x;
    const int o  = blockIdx.x / 19;
    const int t0 = (blockIdx.x % 19) * CH;
    s3m = (const uint64_t*)__builtin_assume_aligned(s3m, 64);
    const float* wrow = wr + (size_t)o * HID;
    float acc[CH];
#pragma unroll
    for (int k = 0; k < CH; ++k) acc[k] = 0.f;
#pragma unroll 4
    for (int i = 0; i < HID; ++i) {
        const float wv = wrow[i];
        const ulonglong4* p =
            (const ulonglong4*)(s3m + (size_t)i * TPAD + t0);
        const ulonglong4 ma = p[0], mb = p[1];
        uint64_t m[CH] = {ma.x, ma.y, ma.z, ma.w, mb.x, mb.y, mb.z, mb.w};
#pragma unroll
        for (int k = 0; k < CH; ++k) {
            float s;
            asm("v_cndmask_b32 %0, 0, %1, %2" : "=v"(s) : "v"(wv), "s"(m[k]));
            acc[k] += s;
        }
    }
#pragma unroll
    for (int k = 0; k < CH; ++k)
        if (t0 + k < TT)
            Y[((size_t)(t0 + k) * OUTN + o) * 64 + lane] = acc[k];
}

// acc[o][b] = sum_t (Y + br[o]) * (1 - ar^(150-t))   (closed-form mr scan)
__global__ void k_racc(const float* __restrict__ Y,
                       const float* __restrict__ br,
                       const float* __restrict__ tau_mr,
                       float* __restrict__ ACC) {
    const int o = blockIdx.x, lane = threadIdx.x;
    const float ar  = 1.f / (1.f + expf(-tau_mr[o]));
    const float bro = br[o];
    float acc = 0.f, q = ar;
    for (int t = TT - 1; t >= 0; --t) {
        const float y = Y[((size_t)t * OUTN + o) * 64 + lane] + bro;
        acc += y * (1.f - q);
        q *= ar;
    }
    ACC[o * 64 + lane] = acc;
}

__global__ void k_smax(const float* __restrict__ ACC, float* __restrict__ out) {
    const int b = threadIdx.x;   // 64 threads
    float v[OUTN];
    float mx = -3.4e38f;
    for (int o = 0; o < OUTN; ++o) {
        v[o] = ACC[o * 64 + b] / (float)TT;
        mx = fmaxf(mx, v[o]);
    }
    float sum = 0.f;
    for (int o = 0; o < OUTN; ++o) sum += expf(v[o] - mx);
    const float lse = mx + logf(sum);
    for (int o = 0; o < OUTN; ++o) out[b * OUTN + o] = v[o] - lse;
}

extern "C" void kernel_launch(void* const* d_in, const int* in_sizes, int n_in,
                              void* d_out, int out_size, void* d_ws,
                              size_t ws_size, hipStream_t stream) {
    (void)in_sizes; (void)n_in; (void)out_size; (void)ws_size;
    const float* x   = (const float*)d_in[0];
    const float* w1  = (const float*)d_in[1];
    const float* b1  = (const float*)d_in[2];
    const float* tm1 = (const float*)d_in[3];
    const float* tn1 = (const float*)d_in[4];
    const float* w2  = (const float*)d_in[5];
    const float* b2  = (const float*)d_in[6];
    const float* tm2 = (const float*)d_in[7];
    const float* tn2 = (const float*)d_in[8];
    const float* w3  = (const float*)d_in[9];
    const float* b3  = (const float*)d_in[10];
    const float* tm3 = (const float*)d_in[11];
    const float* tn3 = (const float*)d_in[12];
    const float* wr  = (const float*)d_in[13];
    const float* br  = (const float*)d_in[14];
    const float* tmr = (const float*)d_in[15];
    const void*  m1  = d_in[16];
    const void*  m2  = d_in[17];
    const void*  m3  = d_in[18];
    float* out = (float*)d_out;

    char* ws = (char*)d_ws;
    float*    xT  = (float*)(ws + XT_OFF);
    uint64_t* s1m = (uint64_t*)(ws + S1_OFF);
    uint64_t* s2m = (uint64_t*)(ws + S2_OFF);
    uint64_t* s3m = (uint64_t*)(ws + S3_OFF);
    float*    Y   = (float*)(ws + Y_OFF);
    float*    ACC = (float*)(ws + ACC_OFF);

    k_tx<<<TT, 256, 0, stream>>>(x, xT);
    k_layer<INSZ, 15, 0><<<HID, 256, 0, stream>>>(
        w1, m1, b1, tm1, tn1, xT, nullptr, s1m);
    k_layer<HID, 128, 1><<<HID, 256, 0, stream>>>(
        w2, m2, b2, tm2, tn2, nullptr, s1m, s2m);
    k_layer<HID, 128, 1><<<HID, 256, 0, stream>>>(
        w3, m3, b3, tm3, tn3, nullptr, s2m, s3m);
    k_ry<<<OUTN * 19, 64, 0, stream>>>(wr, s3m, Y);
    k_racc<<<OUTN, 64, 0, stream>>>(Y, br, tmr, ACC);
    k_smax<<<1, 64, 0, stream>>>(ACC, out);
}

// Round 5
// 1657.340 us; speedup vs baseline: 1.8174x; 1.4809x over previous
//
#include <hip/hip_runtime.h>
#include <stdint.h>

#define BATCH 64
#define TT    150
#define INSZ  120
#define HID   1024
#define OUTN  35
#define NBR   8
#define TPAD  160      // padded T (u64 masks), keeps chunk starts 64B-aligned
#define CH    8        // timesteps per chunk (19 chunks, last has 6 valid)
#define NCHUNK 19

// ---------------- workspace layout (bytes, all 64-aligned) ----------------
#define XT_OFF  0                  // xT  [150][120][64] f32 = 4,608,000
#define S1_OFF  4608000            // s1m [1024][160] u64    = 1,310,720
#define S2_OFF  5918720            // s2m
#define S3_OFF  7229440            // s3m
#define Y_OFF   8540160            // Y   [150][35][64] f32  = 1,344,000
#define ACC_OFF 9884160            // ACC [35][64] f32       = 8,960

// transpose x[b][0][t][i] -> xT[t][i][b], LDS-tiled (both sides coalesced)
__global__ __launch_bounds__(256) void k_tx(const float* __restrict__ x,
                                            float* __restrict__ xT) {
    const int t = blockIdx.x;
    __shared__ float tile[INSZ * 65];
    for (int e = threadIdx.x; e < INSZ * 64; e += 256) {
        const int b = e / INSZ, i = e - b * INSZ;
        tile[i * 65 + b] = x[((size_t)b * TT + t) * INSZ + i];
    }
    __syncthreads();
    for (int e = threadIdx.x; e < INSZ * 64; e += 256) {
        const int i = e >> 6, b = e & 63;
        xT[((size_t)t * INSZ + i) * 64 + b] = tile[i * 65 + b];
    }
}

// One recurrent layer, scans all T steps. grid = HID blocks x 512 threads.
// Block owns 1 neuron (8 branch rows); each wave (64 lanes = 64 batches)
// owns ONE row -> 8192 waves = 32 waves/CU (max occupancy).
// MODE 0: dense float input from xT. MODE 1: spike masks inm[i*TPAD + t].
template <int DIN, int NNZ, int MODE>
__global__ __launch_bounds__(512, 8) void k_layer(
    const float* __restrict__ w,            // [HID*NBR, DIN]
    const void* __restrict__ maskp,         // [HID*NBR, DIN] bool (u8 or i32)
    const float* __restrict__ bias,         // [HID*NBR]
    const float* __restrict__ tau_m,        // [HID]
    const float* __restrict__ tau_n,        // [HID*NBR]
    const float* __restrict__ xin,          // MODE0: [T][DIN][64]
    const uint64_t* __restrict__ inm,       // MODE1: [DIN][TPAD]
    uint64_t* __restrict__ outm)            // [HID][TPAD]
{
    const int tid  = threadIdx.x;
    const int lane = tid & 63;
    const int wid  = tid >> 6;              // 0..7 (branch row)
    const int h    = blockIdx.x;
    const int r    = h * NBR + wid;         // this wave's row

    __shared__ uint2 ent[NBR * NNZ];        // (w bits, idx) per row
    __shared__ float red[2][NBR * CH * 64]; // double-buffered partial sums

    inm = (const uint64_t*)__builtin_assume_aligned(inm, 64);

    // ---- gather masked weights into LDS (ballot compaction) ----
    const unsigned char* m8  = (const unsigned char*)maskp;
    const int*           m32 = (const int*)maskp;
    {
        const int base = wid * NNZ;
        int cnt = 0;
        for (int c = 0; c * 64 < DIN; ++c) {
            const int i = c * 64 + lane;
            int   mv = 0;
            float wv = 0.f;
            if (i < DIN) {
                mv = m8[(size_t)r * DIN + i];
                wv = w[(size_t)r * DIN + i];
            }
            const unsigned long long bal = __ballot(mv != 0);
            const int pos = __popcll(bal & ((1ull << lane) - 1ull));
            if (mv && cnt + pos < NNZ)
                ent[base + cnt + pos] = make_uint2(__float_as_uint(wv), (unsigned)i);
            cnt += __popcll(bal);
        }
        if (cnt != NNZ) {   // masks are int32 after all
            cnt = 0;
            for (int c = 0; c * 64 < DIN; ++c) {
                const int i = c * 64 + lane;
                int   mv = 0;
                float wv = 0.f;
                if (i < DIN) {
                    mv = m32[(size_t)r * DIN + i];
                    wv = w[(size_t)r * DIN + i];
                }
                const unsigned long long bal = __ballot(mv != 0);
                const int pos = __popcll(bal & ((1ull << lane) - 1ull));
                if (mv) ent[base + cnt + pos] =
                            make_uint2(__float_as_uint(wv), (unsigned)i);
                cnt += __popcll(bal);
            }
        }
    }
    __syncthreads();

    const float be = 1.f / (1.f + expf(-tau_n[r]));
    const float om = 1.f - be;
    const float bb = bias[r];
    const float al  = 1.f / (1.f + expf(-tau_m[h]));
    const float oma = 1.f - al;

    float d = 0.f, mem = 0.f, spkprev = 0.f;
    const int base = wid * NNZ;

    for (int tc = 0; tc < NCHUNK; ++tc) {
        const int t0  = tc * CH;
        const int buf = tc & 1;
        float a[CH];
#pragma unroll
        for (int k = 0; k < CH; ++k) a[k] = 0.f;

        if constexpr (MODE == 1) {
#pragma unroll 4
            for (int j = 0; j < NNZ; ++j) {
                const uint2 e  = ent[base + j];
                const int   ix = __builtin_amdgcn_readfirstlane((int)e.y);
                const float wv = __uint_as_float(e.x);
                const ulonglong4* p =
                    (const ulonglong4*)(inm + (size_t)ix * TPAD + t0);
                const ulonglong4 ma = p[0], mb = p[1];
                uint64_t m[CH] = {ma.x, ma.y, ma.z, ma.w,
                                  mb.x, mb.y, mb.z, mb.w};
#pragma unroll
                for (int k = 0; k < CH; ++k) {
                    float s;
                    asm("v_cndmask_b32 %0, 0, %1, %2"
                        : "=v"(s) : "v"(wv), "s"(m[k]));
                    a[k] += s;
                }
            }
        } else {
            const float* xb = xin + (size_t)t0 * DIN * 64;
#pragma unroll 3
            for (int j = 0; j < NNZ; ++j) {
                const uint2 e  = ent[base + j];
                const int   ix = __builtin_amdgcn_readfirstlane((int)e.y);
                const float wv = __uint_as_float(e.x);
#pragma unroll
                for (int k = 0; k < CH; ++k)
                    a[k] += wv * xb[((size_t)k * DIN + ix) * 64 + lane];
            }
        }

        // branch decay (sequential within chunk), stash per-row d
#pragma unroll
        for (int k = 0; k < CH; ++k) {
            d = be * d + om * (a[k] + bb);
            red[buf][(wid * CH + k) * 64 + lane] = d;
        }
        // one barrier per chunk: waves 1..7 run chunk tc+1 into buf^1 while
        // wave 0 reduces buf; buf is rewritten only after the NEXT barrier.
        __syncthreads();

        if (wid == 0) {
#pragma unroll
            for (int k = 0; k < CH; ++k) {
                // EXACT old pair order: ((d0+d1)+(d2+d3))+(d4+d5))+(d6+d7)
                const float r0 = red[buf][(0 * CH + k) * 64 + lane];
                const float r1 = red[buf][(1 * CH + k) * 64 + lane];
                const float r2 = red[buf][(2 * CH + k) * 64 + lane];
                const float r3 = red[buf][(3 * CH + k) * 64 + lane];
                const float r4 = red[buf][(4 * CH + k) * 64 + lane];
                const float r5 = red[buf][(5 * CH + k) * 64 + lane];
                const float r6 = red[buf][(6 * CH + k) * 64 + lane];
                const float r7 = red[buf][(7 * CH + k) * 64 + lane];
                const float p01 = r0 + r1, p23 = r2 + r3;
                const float p45 = r4 + r5, p67 = r6 + r7;
                const float l = ((p01 + p23) + p45) + p67;
                if (t0 + k < TT) {
                    mem = al * mem + oma * l - spkprev;   // VTH = 1.0
                    spkprev = (mem > 1.0f) ? 1.f : 0.f;
                    const unsigned long long bal = __ballot(mem > 1.0f);
                    if (lane == 0) outm[(size_t)h * TPAD + (t0 + k)] = bal;
                }
            }
        }
    }
}

// Y[t][o][b] = wr[o] . s3(t,:,b); 4 waves split the i range (reorder safe:
// readout is linear, no thresholds downstream). wid goes through
// readfirstlane so LLVM knows the mask addresses are uniform (scalar loads,
// required by the "s" asm constraint).
__global__ __launch_bounds__(256) void k_ry(const float* __restrict__ wr,
                                            const uint64_t* __restrict__ s3m,
                                            float* __restrict__ Y) {
    const int lane  = threadIdx.x & 63;
    const int wid   = __builtin_amdgcn_readfirstlane(threadIdx.x >> 6); // 0..3
    const int o  = blockIdx.x / NCHUNK;
    const int t0 = (blockIdx.x % NCHUNK) * CH;
    s3m = (const uint64_t*)__builtin_assume_aligned(s3m, 64);
    const float* wrow = wr + (size_t)o * HID;
    __shared__ float red[4 * CH * 64];
    float acc[CH];
#pragma unroll
    for (int k = 0; k < CH; ++k) acc[k] = 0.f;
#pragma unroll 4
    for (int ii = 0; ii < HID / 4; ++ii) {
        const int i = wid * (HID / 4) + ii;
        const float wv = wrow[i];
        const ulonglong4* p =
            (const ulonglong4*)(s3m + (size_t)i * TPAD + t0);
        const ulonglong4 ma = p[0], mb = p[1];
        uint64_t m[CH] = {ma.x, ma.y, ma.z, ma.w, mb.x, mb.y, mb.z, mb.w};
#pragma unroll
        for (int k = 0; k < CH; ++k) {
            float s;
            asm("v_cndmask_b32 %0, 0, %1, %2" : "=v"(s) : "v"(wv), "s"(m[k]));
            acc[k] += s;
        }
    }
#pragma unroll
    for (int k = 0; k < CH; ++k)
        red[(wid * CH + k) * 64 + lane] = acc[k];
    __syncthreads();
    if (wid == 0) {
#pragma unroll
        for (int k = 0; k < CH; ++k) {
            if (t0 + k >= TT) break;
            const float v = ((red[(0 * CH + k) * 64 + lane]
                            + red[(1 * CH + k) * 64 + lane])
                            + red[(2 * CH + k) * 64 + lane])
                            + red[(3 * CH + k) * 64 + lane];
            Y[((size_t)(t0 + k) * OUTN + o) * 64 + lane] = v;
        }
    }
}

// acc[o][b] = sum_t (Y + br[o]) * (1 - ar^(150-t))   (closed-form mr scan)
__global__ void k_racc(const float* __restrict__ Y,
                       const float* __restrict__ br,
                       const float* __restrict__ tau_mr,
                       float* __restrict__ ACC) {
    const int o = blockIdx.x, lane = threadIdx.x;
    const float ar  = 1.f / (1.f + expf(-tau_mr[o]));
    const float bro = br[o];
    float acc = 0.f, q = ar;
    for (int t = TT - 1; t >= 0; --t) {
        const float y = Y[((size_t)t * OUTN + o) * 64 + lane] + bro;
        acc += y * (1.f - q);
        q *= ar;
    }
    ACC[o * 64 + lane] = acc;
}

__global__ void k_smax(const float* __restrict__ ACC, float* __restrict__ out) {
    const int b = threadIdx.x;   // 64 threads
    float v[OUTN];
    float mx = -3.4e38f;
    for (int o = 0; o < OUTN; ++o) {
        v[o] = ACC[o * 64 + b] / (float)TT;
        mx = fmaxf(mx, v[o]);
    }
    float sum = 0.f;
    for (int o = 0; o < OUTN; ++o) sum += expf(v[o] - mx);
    const float lse = mx + logf(sum);
    for (int o = 0; o < OUTN; ++o) out[b * OUTN + o] = v[o] - lse;
}

extern "C" void kernel_launch(void* const* d_in, const int* in_sizes, int n_in,
                              void* d_out, int out_size, void* d_ws,
                              size_t ws_size, hipStream_t stream) {
    (void)in_sizes; (void)n_in; (void)out_size; (void)ws_size;
    const float* x   = (const float*)d_in[0];
    const float* w1  = (const float*)d_in[1];
    const float* b1  = (const float*)d_in[2];
    const float* tm1 = (const float*)d_in[3];
    const float* tn1 = (const float*)d_in[4];
    const float* w2  = (const float*)d_in[5];
    const float* b2  = (const float*)d_in[6];
    const float* tm2 = (const float*)d_in[7];
    const float* tn2 = (const float*)d_in[8];
    const float* w3  = (const float*)d_in[9];
    const float* b3  = (const float*)d_in[10];
    const float* tm3 = (const float*)d_in[11];
    const float* tn3 = (const float*)d_in[12];
    const float* wr  = (const float*)d_in[13];
    const float* br  = (const float*)d_in[14];
    const float* tmr = (const float*)d_in[15];
    const void*  m1  = d_in[16];
    const void*  m2  = d_in[17];
    const void*  m3  = d_in[18];
    float* out = (float*)d_out;

    char* ws = (char*)d_ws;
    float*    xT  = (float*)(ws + XT_OFF);
    uint64_t* s1m = (uint64_t*)(ws + S1_OFF);
    uint64_t* s2m = (uint64_t*)(ws + S2_OFF);
    uint64_t* s3m = (uint64_t*)(ws + S3_OFF);
    float*    Y   = (float*)(ws + Y_OFF);
    float*    ACC = (float*)(ws + ACC_OFF);

    k_tx<<<TT, 256, 0, stream>>>(x, xT);
    k_layer<INSZ, 15, 0><<<HID, 512, 0, stream>>>(
        w1, m1, b1, tm1, tn1, xT, nullptr, s1m);
    k_layer<HID, 128, 1><<<HID, 512, 0, stream>>>(
        w2, m2, b2, tm2, tn2, nullptr, s1m, s2m);
    k_layer<HID, 128, 1><<<HID, 512, 0, stream>>>(
        w3, m3, b3, tm3, tn3, nullptr, s2m, s3m);
    k_ry<<<OUTN * NCHUNK, 256, 0, stream>>>(wr, s3m, Y);
    k_racc<<<OUTN, 64, 0, stream>>>(Y, br, tmr, ACC);
    k_smax<<<1, 64, 0, stream>>>(ACC, out);
}